// Round 12
// baseline (443.829 us; speedup 1.0000x reference)
//
#include <hip/hip_runtime.h>
#include <math.h>

#define N_NODES 50000
#define N_EDGES 800000
#define ET (N_EDGES + N_NODES)      // 850000 edges incl. self-loops
#define IN_DIM 128
#define HID 64
#define HEADS 4
#define D1 256                      // HID*HEADS
#define NCLS 40
#define NEG_SLOPE 0.2f
#define BN_EPS 1e-5f
#define SM_EPS 1e-16f
#define NB 196                      // ceil(N_NODES/256) scan blocks
#define DEGB 3321                   // ceil(ET/256)
#define XB 6250                     // N_NODES*IN_DIM/4/256 (exact)
#define BNSL 64                     // batchnorm partial-sum slices

typedef unsigned short ushort_t;
typedef __attribute__((ext_vector_type(8))) short short8;
typedef __attribute__((ext_vector_type(16))) float f32x16;

__device__ __forceinline__ float eluf(float x) { return x > 0.f ? x : expm1f(x); }
__device__ __forceinline__ float lrelu(float x) { return x >= 0.f ? x : NEG_SLOPE * x; }
__device__ __forceinline__ unsigned short f2bf(float f) {   // RNE fp32->bf16
    unsigned int u = __float_as_uint(f);
    u += 0x7fffu + ((u >> 16) & 1u);
    return (unsigned short)(u >> 16);
}
__device__ __forceinline__ float bf2f(ushort_t u) {
    return __uint_as_float(((unsigned int)u) << 16);
}

// ---------------------------------------------------------------- prep (fused)
__global__ __launch_bounds__(256) void k_prep(
    const int* __restrict__ ei, int* __restrict__ deg,
    const float* __restrict__ x, ushort_t* __restrict__ xb,
    const float* __restrict__ Wl1, const float* __restrict__ Wr1,
    ushort_t* __restrict__ BT1,
    const float* __restrict__ Wl2, const float* __restrict__ Wr2,
    ushort_t* __restrict__ BT2)
{
    const int b = blockIdx.x, t = threadIdx.x;
    if (b < DEGB) {
        int e = b * 256 + t;
        if (e < ET) {
            int dst = (e < N_EDGES) ? ei[N_EDGES + e] : (e - N_EDGES);
            atomicAdd(&deg[dst], 1);
        }
    } else if (b < DEGB + XB) {
        int i = (b - DEGB) * 256 + t;          // quad index (exact fit)
        float4 v = ((const float4*)x)[i];
        ushort4 o;
        o.x = f2bf(v.x); o.y = f2bf(v.y); o.z = f2bf(v.z); o.w = f2bf(v.w);
        ((ushort4*)xb)[i] = o;
    } else if (b < DEGB + XB + 256) {
        int n = (b - DEGB - XB) * 2 + (t >> 7);  // 0..511
        int k = t & 127;
        float v = (n < 256) ? Wl1[k * 256 + n] : Wr1[k * 256 + (n - 256)];
        BT1[n * 128 + k] = f2bf(v);
    } else {
        int n = b - DEGB - XB - 256;             // 0..127
        int k = t;
        float v = 0.f;
        if (n < 40)      v = Wl2[k * 40 + n];
        else if (n < 80) v = Wr2[k * 40 + (n - 40)];
        BT2[n * 256 + k] = f2bf(v);
    }
}

// ---------------------------------------------------------------- CSR scan
__global__ __launch_bounds__(256) void k_scan1(const int* __restrict__ deg,
                                               int* __restrict__ row_st,
                                               int* __restrict__ bsum) {
    __shared__ int wsum[4], woff[4];
    const int t = threadIdx.x, w = t >> 6, lane = t & 63;
    const int idx = blockIdx.x * 256 + t;
    int v = (idx < N_NODES) ? deg[idx] : 0;
    int s = v;
    #pragma unroll
    for (int off = 1; off < 64; off <<= 1) {
        int y = __shfl_up(s, off, 64);
        if (lane >= off) s += y;
    }
    if (lane == 63) wsum[w] = s;
    __syncthreads();
    if (t == 0) {
        int run = 0;
        #pragma unroll
        for (int i2 = 0; i2 < 4; i2++) { woff[i2] = run; run += wsum[i2]; }
        bsum[blockIdx.x] = run;
    }
    __syncthreads();
    if (idx < N_NODES) row_st[idx] = woff[w] + (s - v);
}

__global__ __launch_bounds__(256) void k_scan3(int* __restrict__ row_st,
                                               int* __restrict__ cursor,
                                               const int* __restrict__ bsum) {
    __shared__ int wred[4];
    const int t = threadIdx.x, w = t >> 6, lane = t & 63;
    int part = 0;
    for (int j = t; j < blockIdx.x; j += 256) part += bsum[j];
    #pragma unroll
    for (int off = 32; off; off >>= 1) part += __shfl_xor(part, off, 64);
    if (lane == 0) wred[w] = part;
    __syncthreads();
    const int pre = wred[0] + wred[1] + wred[2] + wred[3];
    const int idx = blockIdx.x * 256 + t;
    if (idx < N_NODES) {
        int r = row_st[idx] + pre;
        row_st[idx] = r;
        cursor[idx] = r;
    }
    if (idx == 0) row_st[N_NODES] = ET;   // total is a known constant
}

__global__ void k_scatter(const int* __restrict__ ei, int* __restrict__ cursor,
                          int* __restrict__ csr_src) {
    int e = blockIdx.x * blockDim.x + threadIdx.x;
    if (e >= ET) return;
    int src, dst;
    if (e < N_EDGES) { src = ei[e]; dst = ei[N_EDGES + e]; }
    else             { src = dst = e - N_EDGES; }
    int pos = atomicAdd(&cursor[dst], 1);
    csr_src[pos] = src;
}

// ---------------------------------------------------------------- MFMA GEMM
#define MBM 128
#define MBN 128
#define MBK 64
template<typename OT>
__global__ __launch_bounds__(256) void k_mgemm(
    const ushort_t* __restrict__ A, const ushort_t* __restrict__ BT,
    OT* __restrict__ C, int M, int K, int N, int ldc)
{
    __shared__ __align__(16) ushort_t Al[MBM * MBK];   // 16 KB
    __shared__ __align__(16) ushort_t Bl[MBN * MBK];   // 16 KB
    const int t = threadIdx.x;
    const int w = t >> 6, L = t & 63;
    const int i0 = blockIdx.x * MBM;
    const int j0 = blockIdx.y * MBN;
    const int wm = (w >> 1) * 64, wn = (w & 1) * 64;
    const int l31 = L & 31, half = L >> 5;

    int sm[4], sca[4];
    #pragma unroll
    for (int r = 0; r < 4; r++) {
        int s = (r * 4 + w) * 64 + L;      // chunk slot 0..1023
        int m = s >> 3;
        sm[r] = m;
        sca[r] = (s & 7) ^ (m & 7);
    }

    f32x16 acc[2][2];
    #pragma unroll
    for (int a = 0; a < 2; a++)
        #pragma unroll
        for (int b = 0; b < 2; b++)
            #pragma unroll
            for (int r = 0; r < 16; r++) acc[a][b][r] = 0.f;

    for (int kt = 0; kt < K; kt += MBK) {
        short8 sa[4], sb[4];
        #pragma unroll
        for (int r = 0; r < 4; r++) {
            int row = i0 + sm[r]; if (row >= M) row = M - 1;
            sa[r] = *(const short8*)&A[(size_t)row * K + kt + sca[r] * 8];
            sb[r] = *(const short8*)&BT[(size_t)(j0 + sm[r]) * K + kt + sca[r] * 8];
        }
        __syncthreads();
        #pragma unroll
        for (int r = 0; r < 4; r++) {
            int s = (r * 4 + w) * 64 + L;
            *(short8*)&Al[s * 8] = sa[r];
            *(short8*)&Bl[s * 8] = sb[r];
        }
        __syncthreads();
        #pragma unroll
        for (int ks = 0; ks < 4; ks++) {
            short8 af[2], bfr[2];
            #pragma unroll
            for (int mt = 0; mt < 2; mt++) {
                int m = wm + mt * 32 + l31;
                int c = (ks * 2 + half) ^ (m & 7);
                af[mt] = *(const short8*)&Al[(m * 8 + c) * 8];
            }
            #pragma unroll
            for (int nt = 0; nt < 2; nt++) {
                int n = wn + nt * 32 + l31;
                int c = (ks * 2 + half) ^ (n & 7);
                bfr[nt] = *(const short8*)&Bl[(n * 8 + c) * 8];
            }
            #pragma unroll
            for (int mt = 0; mt < 2; mt++)
                #pragma unroll
                for (int nt = 0; nt < 2; nt++)
                    acc[mt][nt] = __builtin_amdgcn_mfma_f32_32x32x16_bf16(
                        af[mt], bfr[nt], acc[mt][nt], 0, 0, 0);
        }
    }
    #pragma unroll
    for (int mt = 0; mt < 2; mt++)
        #pragma unroll
        for (int nt = 0; nt < 2; nt++) {
            int col = j0 + wn + nt * 32 + l31;
            int rbase = i0 + wm + mt * 32 + 4 * half;
            if (col < N) {
                #pragma unroll
                for (int r = 0; r < 16; r++) {
                    int row = rbase + (r & 3) + 8 * (r >> 2);
                    if (row < M) {
                        if constexpr (sizeof(OT) == 2)
                            C[(size_t)row * ldc + col] = (OT)f2bf(acc[mt][nt][r]);
                        else
                            C[(size_t)row * ldc + col] = acc[mt][nt][r];
                    }
                }
            }
        }
}

// BN+ELU fused layer-2 GEMM. R11->R12: A is now bf16 h1b; prologue reduces
// the 64-slice bn partials (replaces the k_bnstats dispatch entirely).
__global__ __launch_bounds__(256) void k_mgemm_bn(
    const ushort_t* __restrict__ A, const ushort_t* __restrict__ BT,
    ushort_t* __restrict__ C, int M, int K, int N, int ldc,
    const float* __restrict__ bn_ps, const float* __restrict__ bn_sq,
    const float* __restrict__ gamma, const float* __restrict__ beta)
{
    __shared__ __align__(16) ushort_t Al[MBM * MBK];
    __shared__ __align__(16) ushort_t Bl[MBN * MBK];
    __shared__ float gsh[256], bsh[256];
    const int t = threadIdx.x;
    const int w = t >> 6, L = t & 63;
    const int i0 = blockIdx.x * MBM;
    const int j0 = blockIdx.y * MBN;
    const int wm = (w >> 1) * 64, wn = (w & 1) * 64;
    const int l31 = L & 31, half = L >> 5;
    {
        float s = 0.f, s2 = 0.f;
        #pragma unroll 8
        for (int j = 0; j < BNSL; j++) {
            s += bn_ps[j * 256 + t];
            s2 += bn_sq[j * 256 + t];
        }
        float mean = s * (1.f / N_NODES);
        float var = s2 * (1.f / N_NODES) - mean * mean;
        float g = gamma[t] * rsqrtf(var + BN_EPS);
        gsh[t] = g;
        bsh[t] = beta[t] - g * mean;
    }
    __syncthreads();

    int sm[4], sca[4];
    #pragma unroll
    for (int r = 0; r < 4; r++) {
        int s = (r * 4 + w) * 64 + L;
        int m = s >> 3;
        sm[r] = m;
        sca[r] = (s & 7) ^ (m & 7);
    }

    f32x16 acc[2][2];
    #pragma unroll
    for (int a = 0; a < 2; a++)
        #pragma unroll
        for (int b = 0; b < 2; b++)
            #pragma unroll
            for (int r = 0; r < 16; r++) acc[a][b][r] = 0.f;

    for (int kt = 0; kt < K; kt += MBK) {
        short8 sa[4], sb[4];
        #pragma unroll
        for (int r = 0; r < 4; r++) {
            int row = i0 + sm[r]; if (row >= M) row = M - 1;
            int kb = kt + sca[r] * 8;
            short8 u = *(const short8*)&A[(size_t)row * K + kb];
            float4 g0 = *(const float4*)&gsh[kb];
            float4 g1 = *(const float4*)&gsh[kb + 4];
            float4 b0 = *(const float4*)&bsh[kb];
            float4 b1v = *(const float4*)&bsh[kb + 4];
            short8 o;
            o[0] = (short)f2bf(eluf(g0.x * bf2f((ushort_t)u[0]) + b0.x));
            o[1] = (short)f2bf(eluf(g0.y * bf2f((ushort_t)u[1]) + b0.y));
            o[2] = (short)f2bf(eluf(g0.z * bf2f((ushort_t)u[2]) + b0.z));
            o[3] = (short)f2bf(eluf(g0.w * bf2f((ushort_t)u[3]) + b0.w));
            o[4] = (short)f2bf(eluf(g1.x * bf2f((ushort_t)u[4]) + b1v.x));
            o[5] = (short)f2bf(eluf(g1.y * bf2f((ushort_t)u[5]) + b1v.y));
            o[6] = (short)f2bf(eluf(g1.z * bf2f((ushort_t)u[6]) + b1v.z));
            o[7] = (short)f2bf(eluf(g1.w * bf2f((ushort_t)u[7]) + b1v.w));
            sa[r] = o;
            sb[r] = *(const short8*)&BT[(size_t)(j0 + sm[r]) * K + kb];
        }
        __syncthreads();
        #pragma unroll
        for (int r = 0; r < 4; r++) {
            int s = (r * 4 + w) * 64 + L;
            *(short8*)&Al[s * 8] = sa[r];
            *(short8*)&Bl[s * 8] = sb[r];
        }
        __syncthreads();
        #pragma unroll
        for (int ks = 0; ks < 4; ks++) {
            short8 af[2], bfr[2];
            #pragma unroll
            for (int mt = 0; mt < 2; mt++) {
                int m = wm + mt * 32 + l31;
                int c = (ks * 2 + half) ^ (m & 7);
                af[mt] = *(const short8*)&Al[(m * 8 + c) * 8];
            }
            #pragma unroll
            for (int nt = 0; nt < 2; nt++) {
                int n = wn + nt * 32 + l31;
                int c = (ks * 2 + half) ^ (n & 7);
                bfr[nt] = *(const short8*)&Bl[(n * 8 + c) * 8];
            }
            #pragma unroll
            for (int mt = 0; mt < 2; mt++)
                #pragma unroll
                for (int nt = 0; nt < 2; nt++)
                    acc[mt][nt] = __builtin_amdgcn_mfma_f32_32x32x16_bf16(
                        af[mt], bfr[nt], acc[mt][nt], 0, 0, 0);
        }
    }
    #pragma unroll
    for (int mt = 0; mt < 2; mt++)
        #pragma unroll
        for (int nt = 0; nt < 2; nt++) {
            int col = j0 + wn + nt * 32 + l31;
            int rbase = i0 + wm + mt * 32 + 4 * half;
            if (col < N) {
                #pragma unroll
                for (int r = 0; r < 16; r++) {
                    int row = rbase + (r & 3) + 8 * (r >> 2);
                    if (row < M)
                        C[(size_t)row * ldc + col] = f2bf(acc[mt][nt][r]);
                }
            }
        }
}

// ---------------------------------------------------------------- layer-1 node kernel
// R11->R12: (a) lrelu(y)=0.6y+0.4|y| with pre-scaled att (|y| is a free VALU
// input modifier -> logit step = add + 2 fma, was add/mul/max/fma).
// (b) batchnorm partials fused into the epilogue: block i atomicAdds its
// row into slice i&63 of bn_ps/bn_sq (replaces the k_bnstats dispatch).
// (c) h1 stored bf16 (write halves; BN math stays fp32 in registers).
#define CH1 16
#define XLS 260   // padded LDS row stride in floats
__global__ __launch_bounds__(256) void k_node1(
    const ushort_t* __restrict__ xlr, const int* __restrict__ row_start,
    const int* __restrict__ csr_src, const float* __restrict__ att1,
    const float* __restrict__ b1, ushort_t* __restrict__ h1b,
    float* __restrict__ bn_ps, float* __restrict__ bn_sq)
{
    __shared__ __align__(16) float xl_sh[CH1 * XLS];   // 16.6 KB
    __shared__ __align__(16) float p_sh[HEADS][CH1];
    const int i = blockIdx.x;
    const int t = threadIdx.x;
    const int h = t >> 6, lane = t & 63;
    const int qe = lane >> 2, qq = lane & 3;
    const int half = lane >> 5, l31 = lane & 31;   // staging mapping
    const int s0 = row_start[i], s1 = row_start[i + 1];
    const int e0 = h * 2 + half, e1 = 8 + h * 2 + half;

    float xr_t[16], at6[16], at4[16];
    {
        const ushort_t* xrp = &xlr[(size_t)i * 512 + 256 + h * 64 + qq * 16];
        const float* atp = &att1[h * 64 + qq * 16];
        #pragma unroll
        for (int k = 0; k < 16; k += 4) {
            ushort4 u = *(const ushort4*)&xrp[k];
            float4 b = *(const float4*)&atp[k];
            xr_t[k + 0] = bf2f(u.x); xr_t[k + 1] = bf2f(u.y);
            xr_t[k + 2] = bf2f(u.z); xr_t[k + 3] = bf2f(u.w);
            at6[k + 0] = 0.6f * b.x; at6[k + 1] = 0.6f * b.y;
            at6[k + 2] = 0.6f * b.z; at6[k + 3] = 0.6f * b.w;
            at4[k + 0] = 0.4f * b.x; at4[k + 1] = 0.4f * b.y;
            at4[k + 2] = 0.4f * b.z; at4[k + 3] = 0.4f * b.w;
        }
    }
    const float bvv = b1[t];

    float acc = 0.f, l_run = 0.f;

    int base = s0;
    const int nfull = (s1 - s0) >> 4;
    int src0 = csr_src[min(s0 + e0, s1 - 1)];
    int src1 = csr_src[min(s0 + e1, s1 - 1)];
    for (int f = 0; f < nfull; f++, base += CH1) {
        __syncthreads();                       // prev chunk agg reads done
        {   // stage two edges with the prefetched src regs
            const ushort_t* gp0 = &xlr[(size_t)src0 * 512];
            ushort4 a0 = *(const ushort4*)&gp0[4 * l31];
            ushort4 a1 = *(const ushort4*)&gp0[128 + 4 * l31];
            const ushort_t* gp1 = &xlr[(size_t)src1 * 512];
            ushort4 c0 = *(const ushort4*)&gp1[4 * l31];
            ushort4 c1 = *(const ushort4*)&gp1[128 + 4 * l31];
            *(float4*)&xl_sh[e0 * XLS + 4 * l31] =
                make_float4(bf2f(a0.x), bf2f(a0.y), bf2f(a0.z), bf2f(a0.w));
            *(float4*)&xl_sh[e0 * XLS + 128 + 4 * l31] =
                make_float4(bf2f(a1.x), bf2f(a1.y), bf2f(a1.z), bf2f(a1.w));
            *(float4*)&xl_sh[e1 * XLS + 4 * l31] =
                make_float4(bf2f(c0.x), bf2f(c0.y), bf2f(c0.z), bf2f(c0.w));
            *(float4*)&xl_sh[e1 * XLS + 128 + 4 * l31] =
                make_float4(bf2f(c1.x), bf2f(c1.y), bf2f(c1.z), bf2f(c1.w));
        }
        __syncthreads();
        // prefetch next chunk's src while compute proceeds
        {
            int nb = base + CH1;
            src0 = csr_src[min(nb + e0, s1 - 1)];
            src1 = csr_src[min(nb + e1, s1 - 1)];
        }
        // logit: edge qe, 16 channels; lrelu via 0.6y + 0.4|y|
        float dot = 0.f;
        {
            const float* xp = &xl_sh[qe * XLS + h * 64 + qq * 16];
            #pragma unroll
            for (int k = 0; k < 16; k += 4) {
                float4 v = *(const float4*)&xp[k];
                float y0 = v.x + xr_t[k + 0], y1 = v.y + xr_t[k + 1];
                float y2 = v.z + xr_t[k + 2], y3 = v.w + xr_t[k + 3];
                dot = __builtin_fmaf(at6[k + 0], y0, __builtin_fmaf(at4[k + 0], __builtin_fabsf(y0), dot));
                dot = __builtin_fmaf(at6[k + 1], y1, __builtin_fmaf(at4[k + 1], __builtin_fabsf(y1), dot));
                dot = __builtin_fmaf(at6[k + 2], y2, __builtin_fmaf(at4[k + 2], __builtin_fabsf(y2), dot));
                dot = __builtin_fmaf(at6[k + 3], y3, __builtin_fmaf(at4[k + 3], __builtin_fabsf(y3), dot));
            }
        }
        dot += __shfl_xor(dot, 1, 64);
        dot += __shfl_xor(dot, 2, 64);
        if (qq == 0) p_sh[h][qe] = __expf(dot);
        float4 P0 = *(const float4*)&p_sh[h][0];
        float4 P1 = *(const float4*)&p_sh[h][4];
        float4 P2 = *(const float4*)&p_sh[h][8];
        float4 P3 = *(const float4*)&p_sh[h][12];
        float p[16] = {P0.x, P0.y, P0.z, P0.w, P1.x, P1.y, P1.z, P1.w,
                       P2.x, P2.y, P2.z, P2.w, P3.x, P3.y, P3.z, P3.w};
        float lsum = 0.f;
        #pragma unroll
        for (int e = 0; e < 16; e++) lsum += p[e];
        l_run += lsum;
        #pragma unroll
        for (int e = 0; e < 16; e++)
            acc += p[e] * xl_sh[e * XLS + t];   // mask-free: all 16 staged
    }
    const int rem = s1 - base;
    if (rem > 0) {
        __syncthreads();
        if (e0 < rem) {
            const ushort_t* gp = &xlr[(size_t)src0 * 512];
            ushort4 u0 = *(const ushort4*)&gp[4 * l31];
            ushort4 u1 = *(const ushort4*)&gp[128 + 4 * l31];
            *(float4*)&xl_sh[e0 * XLS + 4 * l31] =
                make_float4(bf2f(u0.x), bf2f(u0.y), bf2f(u0.z), bf2f(u0.w));
            *(float4*)&xl_sh[e0 * XLS + 128 + 4 * l31] =
                make_float4(bf2f(u1.x), bf2f(u1.y), bf2f(u1.z), bf2f(u1.w));
        }
        if (e1 < rem) {
            const ushort_t* gp = &xlr[(size_t)src1 * 512];
            ushort4 u0 = *(const ushort4*)&gp[4 * l31];
            ushort4 u1 = *(const ushort4*)&gp[128 + 4 * l31];
            *(float4*)&xl_sh[e1 * XLS + 4 * l31] =
                make_float4(bf2f(u0.x), bf2f(u0.y), bf2f(u0.z), bf2f(u0.w));
            *(float4*)&xl_sh[e1 * XLS + 128 + 4 * l31] =
                make_float4(bf2f(u1.x), bf2f(u1.y), bf2f(u1.z), bf2f(u1.w));
        }
        __syncthreads();
        float dot = 0.f;
        {
            const float* xp = &xl_sh[qe * XLS + h * 64 + qq * 16];
            #pragma unroll
            for (int k = 0; k < 16; k += 4) {
                float4 v = *(const float4*)&xp[k];
                float y0 = v.x + xr_t[k + 0], y1 = v.y + xr_t[k + 1];
                float y2 = v.z + xr_t[k + 2], y3 = v.w + xr_t[k + 3];
                dot = __builtin_fmaf(at6[k + 0], y0, __builtin_fmaf(at4[k + 0], __builtin_fabsf(y0), dot));
                dot = __builtin_fmaf(at6[k + 1], y1, __builtin_fmaf(at4[k + 1], __builtin_fabsf(y1), dot));
                dot = __builtin_fmaf(at6[k + 2], y2, __builtin_fmaf(at4[k + 2], __builtin_fabsf(y2), dot));
                dot = __builtin_fmaf(at6[k + 3], y3, __builtin_fmaf(at4[k + 3], __builtin_fabsf(y3), dot));
            }
        }
        dot += __shfl_xor(dot, 1, 64);
        dot += __shfl_xor(dot, 2, 64);
        if (qq == 0) p_sh[h][qe] = (qe < rem) ? __expf(dot) : 0.f;
        for (int e = 0; e < rem; e++) {      // touches only fresh rows
            float pe = p_sh[h][e];
            l_run += pe;
            acc += pe * xl_sh[e * XLS + t];
        }
    }
    const float val = acc / (l_run + SM_EPS) + bvv;
    h1b[(size_t)i * 256 + t] = f2bf(val);
    // batchnorm partials: slice (i & 63), ~780 blocks/slice -> low contention
    const int sl = (i & (BNSL - 1)) * 256 + t;
    atomicAdd(&bn_ps[sl], val);
    atomicAdd(&bn_sq[sl], val * val);
}

// ---------------------------------------------------------------- layer-2 node kernel
// R11->R12: abs-trick lrelu (same as node1); otherwise the R10 full/tail split.
#define C2S 44
__global__ __launch_bounds__(256) void k_node2(
    const ushort_t* __restrict__ xlr2, const int* __restrict__ row_start,
    const int* __restrict__ csr_src, const float* __restrict__ att2,
    const float* __restrict__ b2, float* __restrict__ out)
{
    __shared__ __align__(16) float xl_sh[4][16 * C2S];   // 11.3 KB
    __shared__ __align__(16) float p_sh[4][16];
    __shared__ int src_sh[4][16];
    const int wv = threadIdx.x >> 6, L = threadIdx.x & 63;
    const int i = blockIdx.x * 4 + wv;
    const int qe = L >> 2, qq = L & 3;
    const bool node_ok = (i < N_NODES);
    int s0 = 0, s1 = 0;
    if (node_ok) { s0 = row_start[i]; s1 = row_start[i + 1]; }
    float at6[10], at4[10], xr_t[10];
    #pragma unroll
    for (int r = 0; r < 10; r++) {
        float a = att2[qq + 4 * r];
        at6[r] = 0.6f * a; at4[r] = 0.4f * a;
    }
    if (node_ok) {
        const ushort_t* xrp = &xlr2[(size_t)i * 80 + 40];
        #pragma unroll
        for (int r = 0; r < 10; r++) xr_t[r] = bf2f(xrp[qq + 4 * r]);
    }

    float accv = 0.f, l_run = 0.f;
    const int cagg = (L < NCLS) ? L : 0;
    const int e16 = L & 15, k16 = L >> 4;

    if (node_ok) {
        int base = s0;
        const int nfull = (s1 - s0) >> 4;
        for (int f = 0; f < nfull; f++, base += 16) {
            if (L < 16) src_sh[wv][L] = csr_src[base + L];
            {
                short8 u = *(const short8*)&xlr2[(size_t)src_sh[wv][e16] * 80 + k16 * 8];
                float4 f0 = make_float4(bf2f((ushort_t)u[0]), bf2f((ushort_t)u[1]),
                                        bf2f((ushort_t)u[2]), bf2f((ushort_t)u[3]));
                float4 f1 = make_float4(bf2f((ushort_t)u[4]), bf2f((ushort_t)u[5]),
                                        bf2f((ushort_t)u[6]), bf2f((ushort_t)u[7]));
                *(float4*)&xl_sh[wv][e16 * C2S + k16 * 8] = f0;
                *(float4*)&xl_sh[wv][e16 * C2S + k16 * 8 + 4] = f1;
                if (L < 16) {
                    short8 u2 = *(const short8*)&xlr2[(size_t)src_sh[wv][L] * 80 + 32];
                    float4 g0 = make_float4(bf2f((ushort_t)u2[0]), bf2f((ushort_t)u2[1]),
                                            bf2f((ushort_t)u2[2]), bf2f((ushort_t)u2[3]));
                    float4 g1 = make_float4(bf2f((ushort_t)u2[4]), bf2f((ushort_t)u2[5]),
                                            bf2f((ushort_t)u2[6]), bf2f((ushort_t)u2[7]));
                    *(float4*)&xl_sh[wv][L * C2S + 32] = g0;
                    *(float4*)&xl_sh[wv][L * C2S + 36] = g1;
                }
            }
            float dot = 0.f;
            #pragma unroll
            for (int r = 0; r < 10; r++) {
                float y = xl_sh[wv][qe * C2S + qq + 4 * r] + xr_t[r];
                dot = __builtin_fmaf(at6[r], y, __builtin_fmaf(at4[r], __builtin_fabsf(y), dot));
            }
            dot += __shfl_xor(dot, 1, 64);
            dot += __shfl_xor(dot, 2, 64);
            if (qq == 0) p_sh[wv][qe] = __expf(dot);
            float4 P0 = *(const float4*)&p_sh[wv][0];
            float4 P1 = *(const float4*)&p_sh[wv][4];
            float4 P2 = *(const float4*)&p_sh[wv][8];
            float4 P3 = *(const float4*)&p_sh[wv][12];
            float p[16] = {P0.x, P0.y, P0.z, P0.w, P1.x, P1.y, P1.z, P1.w,
                           P2.x, P2.y, P2.z, P2.w, P3.x, P3.y, P3.z, P3.w};
            float lsum = 0.f;
            #pragma unroll
            for (int e = 0; e < 16; e++) lsum += p[e];
            l_run += lsum;
            #pragma unroll
            for (int e = 0; e < 16; e++)
                accv += p[e] * xl_sh[wv][e * C2S + cagg];
        }
        const int rem = s1 - base;
        if (rem > 0) {
            if (L < rem) src_sh[wv][L] = csr_src[base + L];
            if (e16 < rem) {
                short8 u = *(const short8*)&xlr2[(size_t)src_sh[wv][e16] * 80 + k16 * 8];
                float4 f0 = make_float4(bf2f((ushort_t)u[0]), bf2f((ushort_t)u[1]),
                                        bf2f((ushort_t)u[2]), bf2f((ushort_t)u[3]));
                float4 f1 = make_float4(bf2f((ushort_t)u[4]), bf2f((ushort_t)u[5]),
                                        bf2f((ushort_t)u[6]), bf2f((ushort_t)u[7]));
                *(float4*)&xl_sh[wv][e16 * C2S + k16 * 8] = f0;
                *(float4*)&xl_sh[wv][e16 * C2S + k16 * 8 + 4] = f1;
            }
            if (L < rem) {
                short8 u2 = *(const short8*)&xlr2[(size_t)src_sh[wv][L] * 80 + 32];
                float4 g0 = make_float4(bf2f((ushort_t)u2[0]), bf2f((ushort_t)u2[1]),
                                        bf2f((ushort_t)u2[2]), bf2f((ushort_t)u2[3]));
                float4 g1 = make_float4(bf2f((ushort_t)u2[4]), bf2f((ushort_t)u2[5]),
                                        bf2f((ushort_t)u2[6]), bf2f((ushort_t)u2[7]));
                *(float4*)&xl_sh[wv][L * C2S + 32] = g0;
                *(float4*)&xl_sh[wv][L * C2S + 36] = g1;
            }
            float dot = 0.f;
            #pragma unroll
            for (int r = 0; r < 10; r++) {
                float y = xl_sh[wv][qe * C2S + qq + 4 * r] + xr_t[r];
                dot = __builtin_fmaf(at6[r], y, __builtin_fmaf(at4[r], __builtin_fabsf(y), dot));
            }
            dot += __shfl_xor(dot, 1, 64);
            dot += __shfl_xor(dot, 2, 64);
            if (qq == 0) p_sh[wv][qe] = (qe < rem) ? __expf(dot) : 0.f;
            for (int e = 0; e < rem; e++) {
                float pe = p_sh[wv][e];
                l_run += pe;
                accv += pe * xl_sh[wv][e * C2S + cagg];
            }
        }
    }
    if (node_ok && L < NCLS)
        out[(size_t)i * 40 + L] = accv / (l_run + SM_EPS) + b2[L];
}

// ---------------------------------------------------------------- launch
static inline size_t align_up(size_t v, size_t a) { return (v + a - 1) & ~(a - 1); }

extern "C" void kernel_launch(void* const* d_in, const int* in_sizes, int n_in,
                              void* d_out, int out_size, void* d_ws, size_t ws_size,
                              hipStream_t stream)
{
    const float* x     = (const float*)d_in[0];
    const int*   ei    = (const int*)d_in[1];
    const float* Wl1   = (const float*)d_in[2];
    const float* Wr1   = (const float*)d_in[3];
    const float* att1  = (const float*)d_in[4];
    const float* b1    = (const float*)d_in[5];
    const float* gamma1= (const float*)d_in[6];
    const float* beta1 = (const float*)d_in[7];
    const float* Wl2   = (const float*)d_in[8];
    const float* Wr2   = (const float*)d_in[9];
    const float* att2  = (const float*)d_in[10];
    const float* b2    = (const float*)d_in[11];
    float* out = (float*)d_out;

    char* ws = (char*)d_ws;
    size_t off = 0;
    ushort_t* xlr1b = (ushort_t*)(ws + off); off += (size_t)N_NODES * 512 * 2; // 51.2 MB
    ushort_t* h1b   = (ushort_t*)(ws + off); off += (size_t)N_NODES * 256 * 2; // 25.6 MB
    ushort_t* xb    = (ushort_t*)(ws + off); off += (size_t)N_NODES * IN_DIM * 2; // 12.8 MB
    int*   csr_src = (int*)  (ws + off); off += align_up((size_t)ET * 4, 256);
    int*   row_st  = (int*)  (ws + off); off += align_up((size_t)(N_NODES + 1) * 4, 256);
    int*   cursor  = (int*)  (ws + off); off += align_up((size_t)N_NODES * 4, 256);
    int*   bsum    = (int*)  (ws + off); off += align_up((size_t)NB * 4, 256);
    // contiguous zero-init region: deg | bn_ps | bn_sq (single memset)
    size_t zoff = off;
    int*   deg     = (int*)  (ws + off); off += align_up((size_t)N_NODES * 4, 256);
    float* bn_ps   = (float*)(ws + off); off += (size_t)BNSL * 256 * 4;  // 64 KB
    float* bn_sq   = (float*)(ws + off); off += (size_t)BNSL * 256 * 4;  // 64 KB
    size_t zlen = off - zoff;
    ushort_t* BT1  = (ushort_t*)(ws + off); off += align_up((size_t)512 * 128 * 2, 256);
    ushort_t* BT2  = (ushort_t*)(ws + off); off += align_up((size_t)128 * 256 * 2, 256);
    // overlapped scratch (stream-ordered lifetimes):
    ushort_t* xlr2b = xlr1b;             // 8 MB bf16, written after xlr1b dead

    hipMemsetAsync(ws + zoff, 0, zlen, stream);   // deg + bn_ps + bn_sq

    k_prep<<<DEGB + XB + 256 + 128, 256, 0, stream>>>(
        ei, deg, x, xb, Wl1, Wr1, BT1, Wl2, Wr2, BT2);
    k_scan1<<<NB, 256, 0, stream>>>(deg, row_st, bsum);
    k_scan3<<<NB, 256, 0, stream>>>(row_st, cursor, bsum);
    k_scatter<<<DEGB, 256, 0, stream>>>(ei, cursor, csr_src);

    dim3 g1((N_NODES + MBM - 1) / MBM, 512 / MBN);
    k_mgemm<ushort_t><<<g1, 256, 0, stream>>>(xb, BT1, xlr1b, N_NODES, IN_DIM, 512, 512);
    k_node1<<<N_NODES, 256, 0, stream>>>(xlr1b, row_st, csr_src, att1, b1, h1b,
                                         bn_ps, bn_sq);

    dim3 g2((N_NODES + MBM - 1) / MBM, 1);
    k_mgemm_bn<<<g2, 256, 0, stream>>>(h1b, BT2, xlr2b, N_NODES, D1, 80, 80,
                                       bn_ps, bn_sq, gamma1, beta1);
    k_node2<<<(N_NODES + 3) / 4, 256, 0, stream>>>(xlr2b, row_st, csr_src, att2, b2, out);
}